// Round 6
// baseline (234.937 us; speedup 1.0000x reference)
//
#include <hip/hip_runtime.h>
#include <hip/hip_bf16.h>

#define B_SZ 8
#define N_Q 512
#define M_KV 4096
#define DIM 1024
#define INNER 512
#define NHEADS 8
#define HDIM 64

typedef __attribute__((ext_vector_type(4))) float floatx4;
typedef __attribute__((ext_vector_type(8))) short shortx8;
typedef __attribute__((ext_vector_type(4))) short shortx4;

__device__ inline unsigned short f2bf(float f) {
  union { float f; unsigned u; } x; x.f = f;
  unsigned r = x.u + 0x7FFFu + ((x.u >> 16) & 1u);
  return (unsigned short)(r >> 16);
}

__device__ inline void gload16(const void* g, void* l) {
  __builtin_amdgcn_global_load_lds(
      (const __attribute__((address_space(1))) void*)g,
      (__attribute__((address_space(3))) void*)l, 16, 0, 0);
}

#define BAR()                                            \
  do {                                                   \
    asm volatile("s_waitcnt lgkmcnt(0)" ::: "memory");   \
    __builtin_amdgcn_s_barrier();                        \
    asm volatile("" ::: "memory");                       \
  } while (0)

// W[K][N] fp32 -> Wt[N][K] bf16 (one-time tiny pre-pass)
__global__ void k_transpose_bf16(const float* __restrict__ W,
                                 unsigned short* __restrict__ Wt,
                                 int K, int N) {
  int idx = blockIdx.x * 256 + threadIdx.x;
  if (idx >= K * N) return;
  int n = idx / K, k = idx - n * K;
  Wt[idx] = f2bf(W[(long)k * N + n]);
}

// Rearrange Wkvt [1024][1024] bf16 into gload-ready swizzled K-tiled layout:
// WkvS word idx = ((nt*16+kt)*2048 + w); w -> row=w>>3, pos=w&7,
// content = Wkvt[nt*256+row][kt*64 + ((pos^(row&7))*8) .. +8]
__global__ void k_stage_wkv(const unsigned short* __restrict__ Wkvt,
                            unsigned short* __restrict__ WkvS) {
  int idx = blockIdx.x * 256 + threadIdx.x;  // word index, 0..131071
  int nt = idx >> 15;
  int kt = (idx >> 11) & 15;
  int ww = idx & 2047;
  int row = ww >> 3, pos = ww & 7;
  int c = pos ^ (row & 7);
  const unsigned short* src = Wkvt + ((long)(nt * 256 + row)) * 1024 + kt * 64 + c * 8;
  *reinterpret_cast<shortx8*>(&WkvS[(long)idx * 8]) =
      *reinterpret_cast<const shortx8*>(src);
}

// Dedicated fused-KV GEMM: C[32768,1024] = ctx(fp32)@WkvT. 256x256 tile,
// BK=64, 8 waves (2Mx4N), wave tile 128x64. Raw s_barrier (no vmcnt drain);
// B via global_load_lds from pre-swizzled WkvS; A reg-staged fp32->bf16 with
// swizzled ds_write. Counted-vmcnt semantics via issue order (B before A).
__global__ __launch_bounds__(512, 2)
void k_gemm_kv(const float* __restrict__ Actx,
               const unsigned short* __restrict__ WkvS,
               unsigned short* __restrict__ Kh,
               unsigned short* __restrict__ Vt) {
  __shared__ unsigned short As[2][16384];
  __shared__ unsigned short Bs[2][16384];
  const int tid = threadIdx.x;
  const int lane = tid & 63;
  const int w = tid >> 6;
  const int wr = w >> 2, wc = w & 3;
  const int fr = lane & 15;
  const int fc = lane >> 4;

  // XCD-chunked swizzle: 512 blocks -> 64 per XCD; mt-major within XCD
  const int L = ((blockIdx.x & 7) << 6) + (blockIdx.x >> 3);
  const int mt = L >> 2, nt = L & 3;
  const long arow0 = (long)mt << 8;

  const unsigned short* Bsrc = WkvS + ((long)nt << 18);  // nt*16*2048*8
  const int arow_lo = tid >> 3;                          // 0..63 (+ j*64)
  const int acoff = ((tid & 7) ^ ((tid >> 3) & 7)) << 3; // swizzled k-chunk
  const int ldsA_w0 = (tid << 3);                        // word tid, elems

  floatx4 acc[8][4] = {};

  // ---- prologue: stage tile 0 -> buf 0 (B first, then A; cvt drains both)
  {
    #pragma unroll
    for (int j = 0; j < 4; ++j)
      gload16(Bsrc + (((j * 512 + tid)) << 3),
              &Bs[0][(j * 512 + (w << 6)) << 3]);
    floatx4 a[8];
    #pragma unroll
    for (int j = 0; j < 4; ++j) {
      const float* s = Actx + (arow0 + j * 64 + arow_lo) * 1024 + acoff;
      a[j * 2] = *reinterpret_cast<const floatx4*>(s);
      a[j * 2 + 1] = *reinterpret_cast<const floatx4*>(s + 4);
    }
    #pragma unroll
    for (int j = 0; j < 4; ++j) {
      shortx8 h;
      h[0] = (short)f2bf(a[j * 2][0]); h[1] = (short)f2bf(a[j * 2][1]);
      h[2] = (short)f2bf(a[j * 2][2]); h[3] = (short)f2bf(a[j * 2][3]);
      h[4] = (short)f2bf(a[j * 2 + 1][0]); h[5] = (short)f2bf(a[j * 2 + 1][1]);
      h[6] = (short)f2bf(a[j * 2 + 1][2]); h[7] = (short)f2bf(a[j * 2 + 1][3]);
      *reinterpret_cast<shortx8*>(&As[0][(j * 512 + tid) << 3]) = h;
    }
  }
  BAR();

  for (int t = 0; t < 16; ++t) {
    const int cur = t & 1;
    const bool more = t < 15;
    floatx4 a0[4], a1[4];
    if (more) {
      const unsigned short* bs = Bsrc + ((long)(t + 1) << 14);
      #pragma unroll
      for (int j = 0; j < 4; ++j)
        gload16(bs + ((j * 512 + tid) << 3),
                &Bs[cur ^ 1][(j * 512 + (w << 6)) << 3]);
      const int kn = (t + 1) << 6;
      #pragma unroll
      for (int j = 0; j < 2; ++j) {
        const float* s = Actx + (arow0 + j * 64 + arow_lo) * 1024 + kn + acoff;
        a0[j * 2] = *reinterpret_cast<const floatx4*>(s);
        a0[j * 2 + 1] = *reinterpret_cast<const floatx4*>(s + 4);
      }
    }

    shortx8 bf[4][2];
    #pragma unroll
    for (int nf = 0; nf < 4; ++nf) {
      const int r = wc * 64 + nf * 16 + fr;
      #pragma unroll
      for (int ks = 0; ks < 2; ++ks)
        bf[nf][ks] = *reinterpret_cast<const shortx8*>(
            &Bs[cur][r * 64 + (((ks * 4 + fc) ^ (r & 7)) << 3)]);
    }

    #pragma unroll
    for (int p = 0; p < 4; ++p) {
      shortx8 af[2][2];
      #pragma unroll
      for (int i = 0; i < 2; ++i) {
        const int r = wr * 128 + (p * 2 + i) * 16 + fr;
        #pragma unroll
        for (int ks = 0; ks < 2; ++ks)
          af[i][ks] = *reinterpret_cast<const shortx8*>(
              &As[cur][r * 64 + (((ks * 4 + fc) ^ (r & 7)) << 3)]);
      }
      __builtin_amdgcn_s_setprio(1);
      #pragma unroll
      for (int i = 0; i < 2; ++i) {
        #pragma unroll
        for (int nf = 0; nf < 4; ++nf) {
          #pragma unroll
          for (int ks = 0; ks < 2; ++ks)
            acc[p * 2 + i][nf] = __builtin_amdgcn_mfma_f32_16x16x32_bf16(
                af[i][ks], bf[nf][ks], acc[p * 2 + i][nf], 0, 0, 0);
        }
      }
      __builtin_amdgcn_s_setprio(0);

      if (more && p == 1) {
        // cvt+write half 0 (implicit vmcnt wait drains B gloads + a0)
        #pragma unroll
        for (int j = 0; j < 2; ++j) {
          shortx8 h;
          h[0] = (short)f2bf(a0[j * 2][0]); h[1] = (short)f2bf(a0[j * 2][1]);
          h[2] = (short)f2bf(a0[j * 2][2]); h[3] = (short)f2bf(a0[j * 2][3]);
          h[4] = (short)f2bf(a0[j * 2 + 1][0]); h[5] = (short)f2bf(a0[j * 2 + 1][1]);
          h[6] = (short)f2bf(a0[j * 2 + 1][2]); h[7] = (short)f2bf(a0[j * 2 + 1][3]);
          *reinterpret_cast<shortx8*>(&As[cur ^ 1][(j * 512 + tid) << 3]) = h;
        }
        // issue half 1 loads
        const int kn = (t + 1) << 6;
        #pragma unroll
        for (int j = 2; j < 4; ++j) {
          const float* s = Actx + (arow0 + j * 64 + arow_lo) * 1024 + kn + acoff;
          a1[(j - 2) * 2] = *reinterpret_cast<const floatx4*>(s);
          a1[(j - 2) * 2 + 1] = *reinterpret_cast<const floatx4*>(s + 4);
        }
      }
      if (more && p == 3) {
        #pragma unroll
        for (int j = 2; j < 4; ++j) {
          const int i0 = (j - 2) * 2;
          shortx8 h;
          h[0] = (short)f2bf(a1[i0][0]); h[1] = (short)f2bf(a1[i0][1]);
          h[2] = (short)f2bf(a1[i0][2]); h[3] = (short)f2bf(a1[i0][3]);
          h[4] = (short)f2bf(a1[i0 + 1][0]); h[5] = (short)f2bf(a1[i0 + 1][1]);
          h[6] = (short)f2bf(a1[i0 + 1][2]); h[7] = (short)f2bf(a1[i0 + 1][3]);
          *reinterpret_cast<shortx8*>(&As[cur ^ 1][(j * 512 + tid) << 3]) = h;
        }
      }
    }
    BAR();
  }

  // epilogue: split K / V^T store (branch uniform per block: nt<2 -> K)
  #pragma unroll
  for (int mf = 0; mf < 8; ++mf) {
    #pragma unroll
    for (int nf = 0; nf < 4; ++nf) {
      long gr0 = arow0 + wr * 128 + mf * 16 + fc * 4;
      long gc = (long)nt * 256 + wc * 64 + nf * 16 + fr;
      long b = gr0 >> 12, m = gr0 & 4095;
      if (gc < 512) {
        long h = gc >> 6, d = gc & 63;
        #pragma unroll
        for (int r = 0; r < 4; ++r)
          Kh[((((b * 8 + h) << 12) + m + r) << 6) + d] = f2bf(acc[mf][nf][r]);
      } else {
        long h = (gc - 512) >> 6, d = (gc - 512) & 63;
        shortx4 hv;
        #pragma unroll
        for (int r = 0; r < 4; ++r) hv[r] = (short)f2bf(acc[mf][nf][r]);
        *reinterpret_cast<shortx4*>(&Vt[(((b * 8 + h) * 64 + d) << 12) + m]) = hv;
      }
    }
  }
}

// General GEMM (Q-projection, out-projection). 128x256 tile, 8 waves, BK=32,
// dbuf LDS, corrected 2-way-free swizzle (chunk ^ (row>>1)&3 at 64B rows).
template<int MODE, bool ABF, int NCOL, int MBITS>
__global__ __launch_bounds__(512, 4)
void k_gemm(const void* __restrict__ Ap, const unsigned short* __restrict__ Bt,
            void* __restrict__ Cout, void* __restrict__ Cout2,
            const float* __restrict__ bias, int M, int N, int K, float oscale) {
  __shared__ unsigned short As[2][128 * 32];
  __shared__ unsigned short Bs[2][256 * 32];
  const int tid = threadIdx.x;
  const int lane = tid & 63;
  const int w = tid >> 6;
  const int wr = w >> 2, wc = w & 3;

  const int cpx = gridDim.x >> 3;
  const int L = (blockIdx.x & 7) * cpx + (blockIdx.x >> 3);
  const long arow0 = (long)(L / NCOL) * 128;
  const long bcol0 = (long)(L % NCOL) * 256;

  const float* Af = (const float*)Ap;
  const unsigned short* Ah = (const unsigned short*)Ap;

  const int lsub = lane >> 2;
  const int lchunk = (lane & 3) ^ ((lane >> 3) & 3);
  const long brow0 = bcol0 + (w * 2 + 0) * 16 + lsub;
  const long brow1 = bcol0 + (w * 2 + 1) * 16 + lsub;
  const long ahrow = arow0 + w * 16 + lsub;
  const int arow = tid >> 2;
  const int acseg = tid & 3;
  const int aswz = arow * 32 + ((acseg ^ ((arow >> 1) & 3)) * 8);

  floatx4 acc[4][4] = {};

  #define STAGE_B(buf, kt)                                                   \
    {                                                                        \
      gload16(Bt + brow0 * K + (kt) + lchunk * 8, &Bs[buf][(w * 2) * 512]);  \
      gload16(Bt + brow1 * K + (kt) + lchunk * 8,                            \
              &Bs[buf][(w * 2 + 1) * 512]);                                  \
    }
  #define STAGE_AH(buf, kt) \
    gload16(Ah + ahrow * K + (kt) + lchunk * 8, &As[buf][w * 512]);

  if (ABF) {
    STAGE_AH(0, 0);
  } else {
    const float* src = Af + (arow0 + arow) * (long)K + acseg * 8;
    floatx4 a0 = *reinterpret_cast<const floatx4*>(src);
    floatx4 a1 = *reinterpret_cast<const floatx4*>(src + 4);
    shortx8 h;
    h[0] = (short)f2bf(a0[0]); h[1] = (short)f2bf(a0[1]);
    h[2] = (short)f2bf(a0[2]); h[3] = (short)f2bf(a0[3]);
    h[4] = (short)f2bf(a1[0]); h[5] = (short)f2bf(a1[1]);
    h[6] = (short)f2bf(a1[2]); h[7] = (short)f2bf(a1[3]);
    *reinterpret_cast<shortx8*>(&As[0][aswz]) = h;
  }
  STAGE_B(0, 0);
  __syncthreads();

  const int NK = K >> 5;
  for (int i = 0; i < NK; ++i) {
    const int cur = i & 1;
    const bool more = (i + 1) < NK;
    floatx4 a0, a1;
    if (more) {
      const long ktn = (long)(i + 1) << 5;
      STAGE_B(cur ^ 1, ktn);
      if (ABF) {
        STAGE_AH(cur ^ 1, ktn);
      } else {
        const float* src = Af + (arow0 + arow) * (long)K + ktn + acseg * 8;
        a0 = *reinterpret_cast<const floatx4*>(src);
        a1 = *reinterpret_cast<const floatx4*>(src + 4);
      }
    }

    shortx8 af[4], bf[4];
    #pragma unroll
    for (int rb = 0; rb < 4; ++rb) {
      int row = wr * 64 + rb * 16 + (lane & 15);
      af[rb] = *reinterpret_cast<const shortx8*>(
          &As[cur][row * 32 + (((lane >> 4) ^ ((row >> 1) & 3)) * 8)]);
    }
    #pragma unroll
    for (int cb = 0; cb < 4; ++cb) {
      int row = wc * 64 + cb * 16 + (lane & 15);
      bf[cb] = *reinterpret_cast<const shortx8*>(
          &Bs[cur][row * 32 + (((lane >> 4) ^ ((row >> 1) & 3)) * 8)]);
    }
    #pragma unroll
    for (int rb = 0; rb < 4; ++rb) {
      #pragma unroll
      for (int cb = 0; cb < 4; ++cb)
        acc[rb][cb] = __builtin_amdgcn_mfma_f32_16x16x32_bf16(
            af[rb], bf[cb], acc[rb][cb], 0, 0, 0);
    }

    if (more && !ABF) {
      shortx8 h;
      h[0] = (short)f2bf(a0[0]); h[1] = (short)f2bf(a0[1]);
      h[2] = (short)f2bf(a0[2]); h[3] = (short)f2bf(a0[3]);
      h[4] = (short)f2bf(a1[0]); h[5] = (short)f2bf(a1[1]);
      h[6] = (short)f2bf(a1[2]); h[7] = (short)f2bf(a1[3]);
      *reinterpret_cast<shortx8*>(&As[cur ^ 1][aswz]) = h;
    }
    __syncthreads();
  }
  #undef STAGE_B
  #undef STAGE_AH

  #pragma unroll
  for (int rb = 0; rb < 4; ++rb) {
    #pragma unroll
    for (int cb = 0; cb < 4; ++cb) {
      long gr0 = arow0 + wr * 64 + rb * 16 + (lane >> 4) * 4;
      long gc  = bcol0 + wc * 64 + cb * 16 + (lane & 15);
      if (MODE == 0) {
        float bv = bias[gc];
        #pragma unroll
        for (int r = 0; r < 4; ++r)
          ((float*)Cout)[(gr0 + r) * N + gc] = acc[rb][cb][r] + bv;
      } else if (MODE == 2) {
        long b = gr0 >> MBITS, m = gr0 & ((1 << MBITS) - 1);
        long h = gc >> 6, d = gc & 63;
        #pragma unroll
        for (int r = 0; r < 4; ++r)
          ((unsigned short*)Cout)[((((b * 8 + h) << MBITS) + m + r) << 6) + d] =
              f2bf(acc[rb][cb][r] * oscale);
      }
    }
  }
}

// Flash attention (unchanged from R3 win).
__global__ __launch_bounds__(256, 2)
void k_attn(const unsigned short* __restrict__ Qh,
            const unsigned short* __restrict__ Kh,
            const unsigned short* __restrict__ Vt,
            unsigned short* __restrict__ Aout) {
  __shared__ unsigned short Ks[64][72];
  __shared__ unsigned short Vs[64][72];
  __shared__ unsigned short QPs[64][72];
  const int tid = threadIdx.x;
  const int lane = tid & 63;
  const int w = tid >> 6;
  const int wg = blockIdx.x;
  const int bh = wg & 63;
  const int qt = wg >> 6;
  const int b = bh >> 3, h = bh & 7;

  const unsigned short* Qbase = Qh + (((long)bh << 9) + qt * 64) * 64;
  const unsigned short* Kbase = Kh + (((long)bh) << 18);
  const unsigned short* Vbase = Vt + (((long)bh) << 18);

  const int sr = tid >> 2;
  const int sc = (tid & 3) * 16;

  {
    const unsigned short* src = Qbase + sr * 64 + sc;
    *reinterpret_cast<shortx8*>(&QPs[sr][sc]) =
        *reinterpret_cast<const shortx8*>(src);
    *reinterpret_cast<shortx8*>(&QPs[sr][sc + 8]) =
        *reinterpret_cast<const shortx8*>(src + 8);
  }
  {
    const unsigned short* ksrc = Kbase + sr * 64 + sc;
    *reinterpret_cast<shortx8*>(&Ks[sr][sc]) =
        *reinterpret_cast<const shortx8*>(ksrc);
    *reinterpret_cast<shortx8*>(&Ks[sr][sc + 8]) =
        *reinterpret_cast<const shortx8*>(ksrc + 8);
    const unsigned short* vsrc = Vbase + ((long)sr << 12) + sc;
    *reinterpret_cast<shortx8*>(&Vs[sr][sc]) =
        *reinterpret_cast<const shortx8*>(vsrc);
    *reinterpret_cast<shortx8*>(&Vs[sr][sc + 8]) =
        *reinterpret_cast<const shortx8*>(vsrc + 8);
  }
  __syncthreads();

  shortx8 qf[2];
  qf[0] = *reinterpret_cast<const shortx8*>(
      &QPs[w * 16 + (lane & 15)][(lane >> 4) * 8]);
  qf[1] = *reinterpret_cast<const shortx8*>(
      &QPs[w * 16 + (lane & 15)][32 + (lane >> 4) * 8]);

  floatx4 o_acc[4] = {};
  float l_part[4] = {0.f, 0.f, 0.f, 0.f};
  shortx8 kpre[2], vpre[2];

  for (int mt = 0; mt < M_KV / 64; ++mt) {
    if (mt < M_KV / 64 - 1) {
      const unsigned short* ksrc = Kbase + ((mt + 1) * 64 + sr) * 64 + sc;
      kpre[0] = *reinterpret_cast<const shortx8*>(ksrc);
      kpre[1] = *reinterpret_cast<const shortx8*>(ksrc + 8);
      const unsigned short* vsrc = Vbase + ((long)sr << 12) + (mt + 1) * 64 + sc;
      vpre[0] = *reinterpret_cast<const shortx8*>(vsrc);
      vpre[1] = *reinterpret_cast<const shortx8*>(vsrc + 8);
    }

    floatx4 s[4];
    #pragma unroll
    for (int cb = 0; cb < 4; ++cb) {
      shortx8 k0 = *reinterpret_cast<const shortx8*>(
          &Ks[cb * 16 + (lane & 15)][(lane >> 4) * 8]);
      shortx8 k1 = *reinterpret_cast<const shortx8*>(
          &Ks[cb * 16 + (lane & 15)][32 + (lane >> 4) * 8]);
      floatx4 z = {};
      z = __builtin_amdgcn_mfma_f32_16x16x32_bf16(qf[0], k0, z, 0, 0, 0);
      s[cb] = __builtin_amdgcn_mfma_f32_16x16x32_bf16(qf[1], k1, z, 0, 0, 0);
    }

    #pragma unroll
    for (int cb = 0; cb < 4; ++cb) {
      #pragma unroll
      for (int r = 0; r < 4; ++r) {
        float pv = __expf(s[cb][r]);
        l_part[r] += pv;
        QPs[w * 16 + (lane >> 4) * 4 + r][cb * 16 + (lane & 15)] = f2bf(pv);
      }
    }

    #pragma unroll
    for (int kk = 0; kk < 2; ++kk) {
      shortx8 pf = *reinterpret_cast<const shortx8*>(
          &QPs[w * 16 + (lane & 15)][kk * 32 + (lane >> 4) * 8]);
      #pragma unroll
      for (int db = 0; db < 4; ++db) {
        shortx8 vf = *reinterpret_cast<const shortx8*>(
            &Vs[db * 16 + (lane & 15)][kk * 32 + (lane >> 4) * 8]);
        o_acc[db] = __builtin_amdgcn_mfma_f32_16x16x32_bf16(
            pf, vf, o_acc[db], 0, 0, 0);
      }
    }

    __syncthreads();
    if (mt < M_KV / 64 - 1) {
      *reinterpret_cast<shortx8*>(&Ks[sr][sc]) = kpre[0];
      *reinterpret_cast<shortx8*>(&Ks[sr][sc + 8]) = kpre[1];
      *reinterpret_cast<shortx8*>(&Vs[sr][sc]) = vpre[0];
      *reinterpret_cast<shortx8*>(&Vs[sr][sc + 8]) = vpre[1];
      __syncthreads();
    }
  }

  float inv[4];
  #pragma unroll
  for (int r = 0; r < 4; ++r) {
    float l = l_part[r];
    l += __shfl_xor(l, 1);
    l += __shfl_xor(l, 2);
    l += __shfl_xor(l, 4);
    l += __shfl_xor(l, 8);
    inv[r] = 1.f / l;
  }
  #pragma unroll
  for (int db = 0; db < 4; ++db) {
    #pragma unroll
    for (int r = 0; r < 4; ++r) {
      int n = qt * 64 + w * 16 + (lane >> 4) * 4 + r;
      long idx = ((long)(b * N_Q + n)) * INNER + h * HDIM + db * 16 + (lane & 15);
      Aout[idx] = f2bf(o_acc[db][r] * inv[r]);
    }
  }
}

extern "C" void kernel_launch(void* const* d_in, const int* in_sizes, int n_in,
                              void* d_out, int out_size, void* d_ws, size_t ws_size,
                              hipStream_t stream) {
  const float* x   = (const float*)d_in[0];
  const float* ctx = (const float*)d_in[1];
  const float* Wq  = (const float*)d_in[2];
  const float* Wk  = (const float*)d_in[3];
  const float* Wv  = (const float*)d_in[4];
  const float* Wo  = (const float*)d_in[5];
  const float* bo  = (const float*)d_in[6];
  float* out = (float*)d_out;

  char* ws = (char*)d_ws;
  unsigned short* Qh   = (unsigned short*)(ws);                    // 4MB
  unsigned short* Kh   = (unsigned short*)(ws + (4ull  << 20));    // 32MB
  unsigned short* Vt   = (unsigned short*)(ws + (36ull << 20));    // 32MB
  unsigned short* Aat  = (unsigned short*)(ws + (68ull << 20));    // 4MB (bf16)
  unsigned short* Wqt  = (unsigned short*)(ws + (72ull << 20));    // 1MB
  unsigned short* Wkvt = (unsigned short*)(ws + (73ull << 20));    // 2MB
  unsigned short* Wot  = (unsigned short*)(ws + (75ull << 20));    // 1MB
  unsigned short* WkvS = (unsigned short*)(ws + (76ull << 20));    // 2MB

  k_transpose_bf16<<<(DIM * INNER + 255) / 256, 256, 0, stream>>>(Wq, Wqt, DIM, INNER);
  k_transpose_bf16<<<(DIM * INNER + 255) / 256, 256, 0, stream>>>(Wk, Wkvt, DIM, INNER);
  k_transpose_bf16<<<(DIM * INNER + 255) / 256, 256, 0, stream>>>(
      Wv, Wkvt + (size_t)INNER * DIM, DIM, INNER);
  k_transpose_bf16<<<(INNER * DIM + 255) / 256, 256, 0, stream>>>(Wo, Wot, INNER, DIM);
  k_stage_wkv<<<dim3(512), dim3(256), 0, stream>>>(Wkvt, WkvS);

  // Q projection (head-blocked bf16, pre-scaled 1/8)
  k_gemm<2, false, 2, 9><<<dim3(64), dim3(512), 0, stream>>>(
      x, Wqt, Qh, nullptr, nullptr, B_SZ * N_Q, INNER, DIM, 0.125f);

  // fused K+V projection: 256x256 tiles, pipelined
  k_gemm_kv<<<dim3(512), dim3(512), 0, stream>>>(ctx, WkvS, Kh, Vt);

  k_attn<<<dim3(B_SZ * NHEADS * (N_Q / 64)), dim3(256), 0, stream>>>(Qh, Kh, Vt, Aat);

  // output projection (bf16 A) + bias, fp32 out
  k_gemm<0, true, 4, 0><<<dim3(128), dim3(512), 0, stream>>>(
      Aat, Wot, out, nullptr, bo, B_SZ * N_Q, DIM, INNER, 1.0f);
}